// Round 6
// baseline (1626.457 us; speedup 1.0000x reference)
//
#include <hip/hip_runtime.h>
#include <hip/hip_bf16.h>

// ---------------------------------------------------------------------------
// CNN + EB dropout. Convs = split-bf16 MFMA implicit GEMM over PRE-SPLIT
// bf16 hi/lo NHWC-padded activation buffers. XOR-swizzled LDS (conflict-free).
// This round: XCD-chunked block swizzle + software-pipelined K-loop (loads in
// flight across MFMA phase) + 4 blocks/CU. All compute bit-identical to r5.
// ---------------------------------------------------------------------------

typedef __attribute__((ext_vector_type(8))) short bf16x8;
typedef __attribute__((ext_vector_type(4))) float f32x4;

__device__ __forceinline__ void split_bf16(float x, ushort& h, ushort& l) {
    __hip_bfloat16 bh = __float2bfloat16(x);
    float fh = __bfloat162float(bh);
    __hip_bfloat16 bl = __float2bfloat16(x - fh);
    h = *(ushort*)&bh;
    l = *(ushort*)&bl;
}

// ---------------- zero fill ----------------
__global__ void zero_k(float4* __restrict__ p, int n4) {
    int idx = blockIdx.x * 256 + threadIdx.x;
    int stride = gridDim.x * 256;
    float4 z = {0.f, 0.f, 0.f, 0.f};
    for (int i = idx; i < n4; i += stride) p[i] = z;
}

// ---------------- conv1 weight transpose: out[k*OC+oc]=in[oc*K+k] -----------
__global__ void transw_k(const float* __restrict__ in, float* __restrict__ out,
                         int OC, int K) {
    int idx = blockIdx.x * 256 + threadIdx.x;
    if (idx >= OC * K) return;
    int oc = idx / K, k = idx % K;
    out[k * OC + oc] = in[idx];
}

// ---------------- conv weight split: OIHW -> bf16 hi/lo [oc][tap*IC+ic] -----
__global__ void splitw_k(const float* __restrict__ in, ushort* __restrict__ hi,
                         ushort* __restrict__ lo, int OC, int IC) {
    int idx = blockIdx.x * 256 + threadIdx.x;
    if (idx >= OC * IC * 25) return;
    int oc = idx / (IC * 25);
    int r = idx % (IC * 25);
    int ic = r / 25, tap = r % 25;
    float v = in[idx];
    ushort h, l;
    split_bf16(v, h, l);
    size_t k = (size_t)oc * IC * 25 + tap * IC + ic;
    hi[k] = h;
    lo[k] = l;
}

// ---------------- fc2 weight split (same layout [out][in]) ----------------
__global__ void splitw_fc_k(const float* __restrict__ in, ushort* __restrict__ hi,
                            ushort* __restrict__ lo, int total) {
    int idx = blockIdx.x * 256 + threadIdx.x;
    if (idx >= total) return;
    ushort h, l;
    split_bf16(in[idx], h, l);
    hi[idx] = h;
    lo[idx] = l;
}

// ---------------- conv1: f32 VALU, fused pool, writes pre-split hi/lo -------
__global__ __launch_bounds__(256) void conv1_v3(
        const float* __restrict__ x, const float* __restrict__ w1t,
        const float* __restrict__ b1, ushort* __restrict__ h1hi,
        ushort* __restrict__ h1lo) {
    __shared__ float simg[3 * 34 * 34];   // zero-padded (pad=1)
    __shared__ float c1s[8][904];         // raw conv outputs, 900 px
    const int b = blockIdx.x, oc0 = blockIdx.y * 8, t = threadIdx.x;

    for (int i = t; i < 3 * 34 * 34; i += 256) simg[i] = 0.f;
    __syncthreads();
    for (int i = t; i < 3072; i += 256) {
        int ic = i >> 10, r = (i >> 5) & 31, c = i & 31;
        simg[ic * 1156 + (r + 1) * 34 + (c + 1)] = x[(size_t)b * 3072 + i];
    }
    __syncthreads();

    int base[4];
    bool valid[4];
#pragma unroll
    for (int j = 0; j < 4; j++) {
        int p = t + j * 256;
        valid[j] = p < 900;
        int oh = p / 30, ow = p % 30;
        base[j] = valid[j] ? oh * 34 + ow : 0;
    }

    float acc[4][8];
#pragma unroll
    for (int j = 0; j < 4; j++)
#pragma unroll
        for (int u = 0; u < 8; u++) acc[j][u] = 0.f;

#pragma unroll 1
    for (int ic = 0; ic < 3; ic++) {
        const int icb = ic * 1156;
#pragma unroll 1
        for (int kh = 0; kh < 5; kh++) {
#pragma unroll
            for (int kw = 0; kw < 5; kw++) {
                const float4* wr =
                    (const float4*)&w1t[(ic * 25 + kh * 5 + kw) * 96 + oc0];
                float4 w0 = wr[0], w1v = wr[1];
#pragma unroll
                for (int j = 0; j < 4; j++) {
                    float v = simg[icb + base[j] + kh * 34 + kw];
#pragma unroll
                    for (int u = 0; u < 4; u++) {
                        acc[j][u] = fmaf((&w0.x)[u], v, acc[j][u]);
                        acc[j][u + 4] = fmaf((&w1v.x)[u], v, acc[j][u + 4]);
                    }
                }
            }
        }
    }
#pragma unroll
    for (int j = 0; j < 4; j++)
        if (valid[j]) {
            int p = t + j * 256;
#pragma unroll
            for (int u = 0; u < 8; u++) c1s[u][p] = acc[j][u];
        }
    __syncthreads();
    if (t < 196) {
        const int ph = t / 14, pw = t % 14;
        ushort hv[8], lv[8];
#pragma unroll
        for (int u = 0; u < 8; u++) {
            float m = c1s[u][(2 * ph) * 30 + 2 * pw];
#pragma unroll
            for (int q = 1; q < 9; q++) {
                int dy = q / 3, dx = q % 3;
                m = fmaxf(m, c1s[u][(2 * ph + dy) * 30 + 2 * pw + dx]);
            }
            float o = fmaxf(m + b1[oc0 + u], 0.f);
            split_bf16(o, hv[u], lv[u]);
        }
        size_t ob = (((size_t)b * 18 + ph + 2) * 18 + pw + 2) * 96 + oc0;
        *(bf16x8*)&h1hi[ob] = *(bf16x8*)&hv[0];
        *(bf16x8*)&h1lo[ob] = *(bf16x8*)&lv[0];
    }
}

// ---------------- split-bf16 MFMA implicit-GEMM conv v3 ---------------------
// Flat grid of NM*(OC/128) blocks, XCD-chunked swizzle, software-pipelined
// K-loop. LDS XOR-swizzled [row][8 grans], gran g of row r = part g^(r&7).
template <int BM, int IC, int H, int W, int OH, int OW, int OC, int NM>
__global__ __launch_bounds__(256, 4) void convmfma3_k(
        const ushort* __restrict__ ah, const ushort* __restrict__ al,
        const ushort* __restrict__ wh, const ushort* __restrict__ wl,
        const float* __restrict__ bias, float* __restrict__ C) {
    constexpr int K = 25 * IC;
    constexpr int MI = BM / 32;
    constexpr int G = NM * (OC / 128);
    __shared__ ushort At[BM * 64];
    __shared__ ushort Bt[128 * 64];
    const int t = threadIdx.x;
    const int lane = t & 63, wv = t >> 6;
    // XCD-chunked bijective swizzle (G % 8 == 0)
    const int id = blockIdx.x;
    const int id2 = (id & 7) * (G >> 3) + (id >> 3);
    const int n0 = (id2 / NM) * 128;
    const int m0 = (id2 % NM) * BM;
    const int wm = (wv >> 1) * (BM / 2);
    const int wn = (wv & 1) * 64;

    // staging thread geometry
    const int srow = lane >> 3;          // row-in-group 0..7 (== r&7)
    const int slot = lane & 7;           // stored granule
    const int part = slot ^ srow;        // logical part 0..7
    const bool hiA = part < 4;
    const int pk = (part & 3) * 8;       // k-elem offset within 32-slab

    int arb[MI];
#pragma unroll
    for (int rr = 0; rr < MI; rr++) {
        int r = wv * (BM / 4) + rr * 8 + srow;
        int m = m0 + r;
        int b = m / (OH * OW), pxy = m % (OH * OW);
        int oh = pxy / OW, ow = pxy % OW;
        arb[rr] = ((b * H + oh) * W + ow) * IC + pk;
    }
    const ushort* __restrict__ abase = hiA ? ah : al;
    size_t brb[4];
#pragma unroll
    for (int rr = 0; rr < 4; rr++) {
        int r = wv * 32 + rr * 8 + srow;
        brb[rr] = (size_t)(n0 + r) * K + pk;
    }
    const ushort* __restrict__ bbase = hiA ? wh : wl;

    f32x4 acc[MI][4];
#pragma unroll
    for (int i = 0; i < MI; i++)
#pragma unroll
        for (int j = 0; j < 4; j++) acc[i][j] = (f32x4)(0.f);

    const int q = lane >> 4;     // frag k-gran 0..3
    const int fr = lane & 15;

    // prologue: load slab k0=0 into regs
    bf16x8 sa[MI], sb[4];
    {
        const int koff0 = 0 * IC;  // tap 0 -> (kh=0,kw=0)
#pragma unroll
        for (int rr = 0; rr < MI; rr++)
            sa[rr] = *(const bf16x8*)&abase[arb[rr] + koff0];
#pragma unroll
        for (int rr = 0; rr < 4; rr++)
            sb[rr] = *(const bf16x8*)&bbase[brb[rr]];
    }

    for (int k0 = 0; k0 < K; k0 += 32) {
        __syncthreads();
#pragma unroll
        for (int rr = 0; rr < MI; rr++) {
            int r = wv * (BM / 4) + rr * 8 + srow;
            *(bf16x8*)&At[r * 64 + slot * 8] = sa[rr];
        }
#pragma unroll
        for (int rr = 0; rr < 4; rr++) {
            int r = wv * 32 + rr * 8 + srow;
            *(bf16x8*)&Bt[r * 64 + slot * 8] = sb[rr];
        }
        __syncthreads();

        // issue next slab's global loads (in flight across the MFMA phase)
        const int kn = k0 + 32;
        if (kn < K) {
            const int tap = kn / IC;
            const int koff = ((tap / 5) * W + (tap % 5)) * IC + (kn - tap * IC);
#pragma unroll
            for (int rr = 0; rr < MI; rr++)
                sa[rr] = *(const bf16x8*)&abase[arb[rr] + koff];
#pragma unroll
            for (int rr = 0; rr < 4; rr++)
                sb[rr] = *(const bf16x8*)&bbase[brb[rr] + kn];
        }

        bf16x8 afh[MI], afl[MI], bfh[4], bfl[4];
#pragma unroll
        for (int i = 0; i < MI; i++) {
            int row = wm + fr + i * 16;
            afh[i] = *(const bf16x8*)&At[row * 64 + ((q ^ (row & 7)) << 3)];
            afl[i] = *(const bf16x8*)&At[row * 64 + (((4 | q) ^ (row & 7)) << 3)];
        }
#pragma unroll
        for (int j = 0; j < 4; j++) {
            int row = wn + fr + j * 16;
            bfh[j] = *(const bf16x8*)&Bt[row * 64 + ((q ^ (row & 7)) << 3)];
            bfl[j] = *(const bf16x8*)&Bt[row * 64 + (((4 | q) ^ (row & 7)) << 3)];
        }
#pragma unroll
        for (int i = 0; i < MI; i++)
#pragma unroll
            for (int j = 0; j < 4; j++) {
                acc[i][j] = __builtin_amdgcn_mfma_f32_16x16x32_bf16(
                    afh[i], bfh[j], acc[i][j], 0, 0, 0);
                acc[i][j] = __builtin_amdgcn_mfma_f32_16x16x32_bf16(
                    afh[i], bfl[j], acc[i][j], 0, 0, 0);
                acc[i][j] = __builtin_amdgcn_mfma_f32_16x16x32_bf16(
                    afl[i], bfh[j], acc[i][j], 0, 0, 0);
            }
    }

    const int crow0 = (lane >> 4) * 4;
    const int ccol = lane & 15;
#pragma unroll
    for (int i = 0; i < MI; i++) {
        int gm = m0 + wm + i * 16 + crow0;
#pragma unroll
        for (int j = 0; j < 4; j++) {
            int gn = n0 + wn + j * 16 + ccol;
            float bb = bias[gn];
#pragma unroll
            for (int r = 0; r < 4; r++)
                C[(size_t)(gm + r) * OC + gn] = acc[i][j][r] + bb;
        }
    }
}

// ---------------- pool2: f32 conv2 out -> pre-split hi/lo padded NHWC -------
__global__ void pool2_k(const float* __restrict__ in, ushort* __restrict__ ohi,
                        ushort* __restrict__ olo) {
    int idx = blockIdx.x * 256 + threadIdx.x;
    if (idx >= 512 * 36 * 128) return;
    int c = idx & 127;
    int tmp = idx >> 7;
    int pw = tmp % 6;
    int tmp2 = tmp / 6;
    int ph = tmp2 % 6;
    int b = tmp2 / 6;
    size_t base = (((size_t)b * 14 + 2 * ph) * 14 + 2 * pw) * 128 + c;
    float m = -3.4e38f;
#pragma unroll
    for (int dy = 0; dy < 3; dy++)
#pragma unroll
        for (int dx = 0; dx < 3; dx++)
            m = fmaxf(m, in[base + (dy * 14 + dx) * 128]);
    float v = fmaxf(m, 0.f);
    ushort h, l;
    split_bf16(v, h, l);
    size_t o = (((size_t)b * 10 + ph + 2) * 10 + pw + 2) * 128 + c;
    ohi[o] = h;
    olo[o] = l;
}

// ---------------- pool3: NHWC [512][6][6][256] -> h3 [512][1024] NCHW -------
__global__ void pool3_k(const float* __restrict__ in, float* __restrict__ h3) {
    int idx = blockIdx.x * 256 + threadIdx.x;
    if (idx >= 512 * 4 * 256) return;
    int c = idx & 255;
    int pw = (idx >> 8) & 1;
    int ph = (idx >> 9) & 1;
    int b = idx >> 10;
    size_t base = (((size_t)b * 6 + 2 * ph) * 6 + 2 * pw) * 256 + c;
    float m = -3.4e38f;
#pragma unroll
    for (int dy = 0; dy < 3; dy++)
#pragma unroll
        for (int dx = 0; dx < 3; dx++)
            m = fmaxf(m, in[base + (dy * 6 + dx) * 256]);
    h3[(size_t)b * 1024 + c * 4 + ph * 2 + pw] = fmaxf(m, 0.f);
}

// ---------------- 64x64 tiled f32 GEMM (FC layers) --------------------------
template <int TRANSB, int RELUW, int BIAS, int RELUOUT, int DUAL>
__global__ __launch_bounds__(256) void gemm_k(
        const float* __restrict__ A, const float* __restrict__ Bm,
        const float* __restrict__ bias, float* __restrict__ C,
        float* __restrict__ C2, int K, int N) {
    __shared__ float As[16][68];
    __shared__ float Bs[16][68];
    __shared__ float Bs2[DUAL ? 16 : 1][68];
    const int t = threadIdx.x;
    const int n0 = blockIdx.x * 64;
    const int m0 = blockIdx.y * 64;
    const int tm = t & 15, tn = t >> 4;

    float acc[16];
    float acc2[DUAL ? 16 : 1];
#pragma unroll
    for (int i = 0; i < 16; i++) acc[i] = 0.f;
    if constexpr (DUAL) {
#pragma unroll
        for (int i = 0; i < 16; i++) acc2[i] = 0.f;
    }

    const int ar = t >> 2, ak = (t & 3) << 2;
    const int bk = t >> 4, bn = (t & 15) << 2;

    for (int k0 = 0; k0 < K; k0 += 16) {
        float4 av = *(const float4*)&A[(size_t)(m0 + ar) * K + k0 + ak];
        float4 bv;
        if constexpr (TRANSB) {
            bv = *(const float4*)&Bm[(size_t)(n0 + ar) * K + k0 + ak];
        } else {
            bv = *(const float4*)&Bm[(size_t)(k0 + bk) * N + n0 + bn];
        }
        if constexpr (RELUW) {
            bv.x = fmaxf(bv.x, 0.f); bv.y = fmaxf(bv.y, 0.f);
            bv.z = fmaxf(bv.z, 0.f); bv.w = fmaxf(bv.w, 0.f);
        }
        __syncthreads();
        As[ak + 0][ar] = av.x; As[ak + 1][ar] = av.y;
        As[ak + 2][ar] = av.z; As[ak + 3][ar] = av.w;
        if constexpr (TRANSB) {
            Bs[ak + 0][ar] = bv.x; Bs[ak + 1][ar] = bv.y;
            Bs[ak + 2][ar] = bv.z; Bs[ak + 3][ar] = bv.w;
            if constexpr (DUAL) {
                Bs2[ak + 0][ar] = fmaxf(bv.x, 0.f);
                Bs2[ak + 1][ar] = fmaxf(bv.y, 0.f);
                Bs2[ak + 2][ar] = fmaxf(bv.z, 0.f);
                Bs2[ak + 3][ar] = fmaxf(bv.w, 0.f);
            }
        } else {
            *(float4*)&Bs[bk][bn] = bv;
        }
        __syncthreads();
#pragma unroll
        for (int kk = 0; kk < 16; kk++) {
            float4 a4 = *(const float4*)&As[kk][tm * 4];
            float4 b4 = *(const float4*)&Bs[kk][tn * 4];
            const float* ap = &a4.x;
            const float* bp = &b4.x;
            if constexpr (DUAL) {
                float4 b4p = *(const float4*)&Bs2[kk][tn * 4];
                const float* bpp = &b4p.x;
#pragma unroll
                for (int i = 0; i < 4; i++)
#pragma unroll
                    for (int j = 0; j < 4; j++) {
                        acc[i * 4 + j] = fmaf(ap[i], bp[j], acc[i * 4 + j]);
                        acc2[i * 4 + j] = fmaf(ap[i], bpp[j], acc2[i * 4 + j]);
                    }
            } else {
#pragma unroll
                for (int i = 0; i < 4; i++)
#pragma unroll
                    for (int j = 0; j < 4; j++)
                        acc[i * 4 + j] = fmaf(ap[i], bp[j], acc[i * 4 + j]);
            }
        }
    }

#pragma unroll
    for (int i = 0; i < 4; i++) {
        size_t row = (size_t)(m0 + tm * 4 + i) * N + n0 + tn * 4;
        float4 o;
#pragma unroll
        for (int j = 0; j < 4; j++) {
            float v = acc[i * 4 + j];
            if constexpr (BIAS) v += bias[n0 + tn * 4 + j];
            if constexpr (RELUOUT) v = fmaxf(v, 0.f);
            (&o.x)[j] = v;
        }
        *(float4*)&C[row] = o;
        if constexpr (DUAL) {
            float4 o2;
#pragma unroll
            for (int j = 0; j < 4; j++) (&o2.x)[j] = acc2[i * 4 + j];
            *(float4*)&C2[row] = o2;
        }
    }
}

// ---------------- h6 GEMM: split-bf16 MFMA, BM=64 BN=64 ---------------------
__global__ __launch_bounds__(256, 2) void gemmh6_k(
        const float* __restrict__ A, const ushort* __restrict__ wh,
        const ushort* __restrict__ wl, const float* __restrict__ bias,
        float* __restrict__ C) {
    __shared__ ushort Ah[64][40];
    __shared__ ushort Al[64][40];
    __shared__ ushort Bh[64][40];
    __shared__ ushort Bl[64][40];
    const int t = threadIdx.x;
    const int n0 = blockIdx.x * 64;
    const int m0 = blockIdx.y * 64;
    const int lane = t & 63, wv = t >> 6;
    const int wm = (wv >> 1) * 32, wn = (wv & 1) * 32;
    const int row = t & 63, kq = t >> 6;

    f32x4 acc[2][2];
#pragma unroll
    for (int i = 0; i < 2; i++)
#pragma unroll
        for (int j = 0; j < 2; j++) acc[i][j] = (f32x4)(0.f);

    const int kp = (lane >> 4) * 8;

    for (int k0 = 0; k0 < 2048; k0 += 32) {
        float4 a0 = *(const float4*)&A[(size_t)(m0 + row) * 2048 + k0 + kq * 8];
        float4 a1 = *(const float4*)&A[(size_t)(m0 + row) * 2048 + k0 + kq * 8 + 4];
        bf16x8 bh8 = *(const bf16x8*)&wh[(size_t)(n0 + row) * 2048 + k0 + kq * 8];
        bf16x8 bl8 = *(const bf16x8*)&wl[(size_t)(n0 + row) * 2048 + k0 + kq * 8];
        __syncthreads();
        ushort4 h0, l0, h1, l1;
        split_bf16(a0.x, h0.x, l0.x); split_bf16(a0.y, h0.y, l0.y);
        split_bf16(a0.z, h0.z, l0.z); split_bf16(a0.w, h0.w, l0.w);
        split_bf16(a1.x, h1.x, l1.x); split_bf16(a1.y, h1.y, l1.y);
        split_bf16(a1.z, h1.z, l1.z); split_bf16(a1.w, h1.w, l1.w);
        *(ushort4*)&Ah[row][kq * 8] = h0;
        *(ushort4*)&Ah[row][kq * 8 + 4] = h1;
        *(ushort4*)&Al[row][kq * 8] = l0;
        *(ushort4*)&Al[row][kq * 8 + 4] = l1;
        *(bf16x8*)&Bh[row][kq * 8] = bh8;
        *(bf16x8*)&Bl[row][kq * 8] = bl8;
        __syncthreads();

        bf16x8 afh[2], afl[2], bfh[2], bfl[2];
#pragma unroll
        for (int i = 0; i < 2; i++) {
            afh[i] = *(bf16x8*)&Ah[wm + i * 16 + (lane & 15)][kp];
            afl[i] = *(bf16x8*)&Al[wm + i * 16 + (lane & 15)][kp];
            bfh[i] = *(bf16x8*)&Bh[wn + i * 16 + (lane & 15)][kp];
            bfl[i] = *(bf16x8*)&Bl[wn + i * 16 + (lane & 15)][kp];
        }
#pragma unroll
        for (int i = 0; i < 2; i++)
#pragma unroll
            for (int j = 0; j < 2; j++) {
                acc[i][j] = __builtin_amdgcn_mfma_f32_16x16x32_bf16(
                    afh[i], bfh[j], acc[i][j], 0, 0, 0);
                acc[i][j] = __builtin_amdgcn_mfma_f32_16x16x32_bf16(
                    afh[i], bfl[j], acc[i][j], 0, 0, 0);
                acc[i][j] = __builtin_amdgcn_mfma_f32_16x16x32_bf16(
                    afl[i], bfh[j], acc[i][j], 0, 0, 0);
            }
    }

#pragma unroll
    for (int i = 0; i < 2; i++) {
        int gm = m0 + wm + i * 16 + (lane >> 4) * 4;
#pragma unroll
        for (int j = 0; j < 2; j++) {
            int gn = n0 + wn + j * 16 + (lane & 15);
            float bb = bias[gn];
#pragma unroll
            for (int r = 0; r < 4; r++)
                C[(size_t)(gm + r) * 2048 + gn] = fmaxf(acc[i][j][r] + bb, 0.f);
        }
    }
}

// ---------------- zlab[b] = dot(h6_eb[b], relu(W3[label[b]])) ----------------
__global__ __launch_bounds__(256) void zlab_k(
        const float* __restrict__ h6eb, const float* __restrict__ w3,
        const int* __restrict__ label, float* __restrict__ zlab) {
    __shared__ float red[4];
    const int b = blockIdx.x, t = threadIdx.x;
    const int lab = label[b];
    const float4* hp = (const float4*)(h6eb + (size_t)b * 2048);
    const float4* wp = (const float4*)(w3 + (size_t)lab * 2048);
    float s = 0.f;
    for (int i = t; i < 512; i += 256) {
        float4 h = hp[i], w = wp[i];
        s += h.x * fmaxf(w.x, 0.f) + h.y * fmaxf(w.y, 0.f) +
             h.z * fmaxf(w.z, 0.f) + h.w * fmaxf(w.w, 0.f);
    }
#pragma unroll
    for (int off = 32; off > 0; off >>= 1) s += __shfl_down(s, off, 64);
    if ((t & 63) == 0) red[t >> 6] = s;
    __syncthreads();
    if (t == 0) zlab[b] = red[0] + red[1] + red[2] + red[3];
}

// ---------------- s2 elementwise ----------------
__global__ void s2_k(const float* __restrict__ h6eb, const float* __restrict__ z2,
                     const float* __restrict__ w3, const int* __restrict__ label,
                     const float* __restrict__ zlab, float* __restrict__ s2) {
    int idx = blockIdx.x * 256 + threadIdx.x;
    int b = idx >> 11, j = idx & 2047;
    float zl = zlab[b], zv = z2[idx];
    float v = 0.f;
    if (zl > 0.f && zv > 0.f) {
        float wp = fmaxf(w3[(size_t)label[b] * 2048 + j], 0.f);
        v = h6eb[idx] * wp / (zl * zv);
    }
    s2[idx] = v;
}

// ---------------- excitation dropout ----------------
__global__ void edrop_k(const float* __restrict__ h5, const float* __restrict__ t,
                        const float* __restrict__ noise, float* __restrict__ hed) {
    int idx = blockIdx.x * 256 + threadIdx.x;
    float pe = h5[idx] * t[idx];
    float num = 1023.5f * pe;
    float retain = 1.f - num / (num + 0.5f * (1.f - pe));
    float m = (noise[idx] < retain) ? 1.f : 0.f;
    hed[idx] = (retain > 0.f) ? h5[idx] * m / retain : 0.f;
}

// ---------------- final fc3 ----------------
__global__ void fc3_out_k(const float* __restrict__ h6, const float* __restrict__ w,
                          const float* __restrict__ bias, float* __restrict__ out) {
    int idx = blockIdx.x * 256 + threadIdx.x;
    if (idx >= 5120) return;
    int b = idx / 10, c = idx % 10;
    const float4* hp = (const float4*)(h6 + (size_t)b * 2048);
    const float4* wp = (const float4*)(w + (size_t)c * 2048);
    float s = 0.f;
    for (int i = 0; i < 512; i++) {
        float4 h = hp[i], ww = wp[i];
        s += h.x * ww.x + h.y * ww.y + h.z * ww.z + h.w * ww.w;
    }
    out[idx] = s + bias[c];
}

// ---------------------------------------------------------------------------
extern "C" void kernel_launch(void* const* d_in, const int* in_sizes, int n_in,
                              void* d_out, int out_size, void* d_ws, size_t ws_size,
                              hipStream_t stream) {
    const float* x       = (const float*)d_in[0];
    const float* noise   = (const float*)d_in[1];
    const float* conv1_w = (const float*)d_in[2];
    const float* conv1_b = (const float*)d_in[3];
    const float* conv2_w = (const float*)d_in[4];
    const float* conv2_b = (const float*)d_in[5];
    const float* conv3_w = (const float*)d_in[6];
    const float* conv3_b = (const float*)d_in[7];
    const float* fc1_w   = (const float*)d_in[8];
    const float* fc1_b   = (const float*)d_in[9];
    const float* fc2_w   = (const float*)d_in[10];
    const float* fc2_b   = (const float*)d_in[11];
    const float* fc3_w   = (const float*)d_in[12];
    const float* fc3_b   = (const float*)d_in[13];
    const int*   label   = (const int*)d_in[14];
    float* out = (float*)d_out;

    const size_t N_H1 = (size_t)512 * 18 * 18 * 96;   // 15,925,248 elems
    const size_t N_C2 = (size_t)512 * 14 * 14 * 128;  // 12,845,056
    const size_t N_H2 = (size_t)512 * 10 * 10 * 128;  //  6,553,600
    const size_t N_H3 = (size_t)512 * 1024;

    float* ws = (float*)d_ws;
    ushort* h1hi = (ushort*)ws;
    ushort* h1lo = h1hi + N_H1;
    float* c3 = ws;                       // aliases h1 region after conv2
    float* c2 = ws + N_H1;                // N_C2 floats
    float* h5   = c2;                     // fc buffers alias c2 (dead after pool2)
    float* h6eb = c2 + 1 * 1048576;
    float* z2   = c2 + 2 * 1048576;
    float* s2   = c2 + 3 * 1048576;
    float* tb   = c2 + 4 * 1048576;
    float* hed  = c2 + 5 * 1048576;
    float* h6   = c2 + 6 * 1048576;
    float* zlab = c2 + 7 * 1048576;
    ushort* h2hi = (ushort*)(ws + N_H1 + N_C2);
    ushort* h2lo = h2hi + N_H2;
    float* h3  = ws + N_H1 + N_C2 + N_H2;
    float* w1t = h3 + N_H3;                        // 7,200 floats
    ushort* w2sh = (ushort*)(w1t + 7200);
    ushort* w2sl = w2sh + 307200;
    ushort* w3sh = w2sl + 307200;
    ushort* w3sl = w3sh + 819200;
    ushort* w2fh = w3sl + 819200;
    ushort* w2fl = w2fh + 4194304;

    // weight prep
    transw_k<<<(75 * 96 + 255) / 256, 256, 0, stream>>>(conv1_w, w1t, 96, 75);
    splitw_k<<<(307200 + 255) / 256, 256, 0, stream>>>(conv2_w, w2sh, w2sl, 128, 96);
    splitw_k<<<(819200 + 255) / 256, 256, 0, stream>>>(conv3_w, w3sh, w3sl, 256, 128);
    splitw_fc_k<<<16384, 256, 0, stream>>>(fc2_w, w2fh, w2fl, 4194304);

    // zero padded hi/lo buffers
    zero_k<<<2048, 256, 0, stream>>>((float4*)h1hi, (int)(N_H1 / 4));
    zero_k<<<2048, 256, 0, stream>>>((float4*)h2hi, (int)(N_H2 / 4));

    // conv stack
    conv1_v3<<<dim3(512, 12), 256, 0, stream>>>(x, w1t, conv1_b, h1hi, h1lo);
    // conv2: M=100352, BM=128, NM=784, OC=128 -> 784 blocks
    convmfma3_k<128, 96, 18, 18, 14, 14, 128, 784><<<784, 256, 0, stream>>>(
        h1hi, h1lo, w2sh, w2sl, conv2_b, c2);
    pool2_k<<<(512 * 36 * 128 + 255) / 256, 256, 0, stream>>>(c2, h2hi, h2lo);
    // conv3: M=18432, BM=64, NM=288, OC=256 -> 576 blocks
    convmfma3_k<64, 128, 10, 10, 6, 6, 256, 288><<<576, 256, 0, stream>>>(
        h2hi, h2lo, w3sh, w3sl, conv3_b, c3);
    pool3_k<<<(512 * 4 * 256 + 255) / 256, 256, 0, stream>>>(c3, h3);

    // fc1
    gemm_k<1, 0, 1, 1, 0><<<dim3(32, 8), 256, 0, stream>>>(
        h3, fc1_w, fc1_b, h5, nullptr, 1024, 2048);

    // dual: h6_eb, z2
    gemm_k<1, 0, 1, 1, 1><<<dim3(32, 8), 256, 0, stream>>>(
        h5, fc2_w, fc2_b, h6eb, z2, 2048, 2048);

    // EB collapse
    zlab_k<<<512, 256, 0, stream>>>(h6eb, fc3_w, label, zlab);
    s2_k<<<4096, 256, 0, stream>>>(h6eb, z2, fc3_w, label, zlab, s2);

    // t = s2 @ relu(W2)
    gemm_k<0, 1, 0, 0, 0><<<dim3(32, 8), 256, 0, stream>>>(
        s2, fc2_w, nullptr, tb, nullptr, 2048, 2048);

    // excitation dropout
    edrop_k<<<4096, 256, 0, stream>>>(h5, tb, noise, hed);

    // h6 = relu(h_ed W2^T + b)  -- post-mask: MFMA safe
    gemmh6_k<<<dim3(32, 8), 256, 0, stream>>>(hed, w2fh, w2fl, fc2_b, h6);

    // out
    fc3_out_k<<<20, 256, 0, stream>>>(h6, fc3_w, fc3_b, out);
}

// Round 7
// 1040.994 us; speedup vs baseline: 1.5624x; 1.5624x over previous
//
#include <hip/hip_runtime.h>
#include <hip/hip_bf16.h>

// ---------------------------------------------------------------------------
// CNN + EB dropout. Convs = split-bf16 MFMA implicit GEMM over PRE-SPLIT
// bf16 hi/lo NHWC-padded activation buffers. XOR-swizzled LDS (conflict-free).
// r7 = r5 kernel body (no reg pipeline, launch_bounds(256,2) -- r6's spill
// regression reverted) + XCD-chunked block swizzle for L2 locality.
// ---------------------------------------------------------------------------

typedef __attribute__((ext_vector_type(8))) short bf16x8;
typedef __attribute__((ext_vector_type(4))) float f32x4;

__device__ __forceinline__ void split_bf16(float x, ushort& h, ushort& l) {
    __hip_bfloat16 bh = __float2bfloat16(x);
    float fh = __bfloat162float(bh);
    __hip_bfloat16 bl = __float2bfloat16(x - fh);
    h = *(ushort*)&bh;
    l = *(ushort*)&bl;
}

// ---------------- zero fill ----------------
__global__ void zero_k(float4* __restrict__ p, int n4) {
    int idx = blockIdx.x * 256 + threadIdx.x;
    int stride = gridDim.x * 256;
    float4 z = {0.f, 0.f, 0.f, 0.f};
    for (int i = idx; i < n4; i += stride) p[i] = z;
}

// ---------------- conv1 weight transpose: out[k*OC+oc]=in[oc*K+k] -----------
__global__ void transw_k(const float* __restrict__ in, float* __restrict__ out,
                         int OC, int K) {
    int idx = blockIdx.x * 256 + threadIdx.x;
    if (idx >= OC * K) return;
    int oc = idx / K, k = idx % K;
    out[k * OC + oc] = in[idx];
}

// ---------------- conv weight split: OIHW -> bf16 hi/lo [oc][tap*IC+ic] -----
__global__ void splitw_k(const float* __restrict__ in, ushort* __restrict__ hi,
                         ushort* __restrict__ lo, int OC, int IC) {
    int idx = blockIdx.x * 256 + threadIdx.x;
    if (idx >= OC * IC * 25) return;
    int oc = idx / (IC * 25);
    int r = idx % (IC * 25);
    int ic = r / 25, tap = r % 25;
    float v = in[idx];
    ushort h, l;
    split_bf16(v, h, l);
    size_t k = (size_t)oc * IC * 25 + tap * IC + ic;
    hi[k] = h;
    lo[k] = l;
}

// ---------------- fc2 weight split (same layout [out][in]) ----------------
__global__ void splitw_fc_k(const float* __restrict__ in, ushort* __restrict__ hi,
                            ushort* __restrict__ lo, int total) {
    int idx = blockIdx.x * 256 + threadIdx.x;
    if (idx >= total) return;
    ushort h, l;
    split_bf16(in[idx], h, l);
    hi[idx] = h;
    lo[idx] = l;
}

// ---------------- conv1: f32 VALU, fused pool, writes pre-split hi/lo -------
__global__ __launch_bounds__(256) void conv1_v3(
        const float* __restrict__ x, const float* __restrict__ w1t,
        const float* __restrict__ b1, ushort* __restrict__ h1hi,
        ushort* __restrict__ h1lo) {
    __shared__ float simg[3 * 34 * 34];   // zero-padded (pad=1)
    __shared__ float c1s[8][904];         // raw conv outputs, 900 px
    const int b = blockIdx.x, oc0 = blockIdx.y * 8, t = threadIdx.x;

    for (int i = t; i < 3 * 34 * 34; i += 256) simg[i] = 0.f;
    __syncthreads();
    for (int i = t; i < 3072; i += 256) {
        int ic = i >> 10, r = (i >> 5) & 31, c = i & 31;
        simg[ic * 1156 + (r + 1) * 34 + (c + 1)] = x[(size_t)b * 3072 + i];
    }
    __syncthreads();

    int base[4];
    bool valid[4];
#pragma unroll
    for (int j = 0; j < 4; j++) {
        int p = t + j * 256;
        valid[j] = p < 900;
        int oh = p / 30, ow = p % 30;
        base[j] = valid[j] ? oh * 34 + ow : 0;
    }

    float acc[4][8];
#pragma unroll
    for (int j = 0; j < 4; j++)
#pragma unroll
        for (int u = 0; u < 8; u++) acc[j][u] = 0.f;

#pragma unroll 1
    for (int ic = 0; ic < 3; ic++) {
        const int icb = ic * 1156;
#pragma unroll 1
        for (int kh = 0; kh < 5; kh++) {
#pragma unroll
            for (int kw = 0; kw < 5; kw++) {
                const float4* wr =
                    (const float4*)&w1t[(ic * 25 + kh * 5 + kw) * 96 + oc0];
                float4 w0 = wr[0], w1v = wr[1];
#pragma unroll
                for (int j = 0; j < 4; j++) {
                    float v = simg[icb + base[j] + kh * 34 + kw];
#pragma unroll
                    for (int u = 0; u < 4; u++) {
                        acc[j][u] = fmaf((&w0.x)[u], v, acc[j][u]);
                        acc[j][u + 4] = fmaf((&w1v.x)[u], v, acc[j][u + 4]);
                    }
                }
            }
        }
    }
#pragma unroll
    for (int j = 0; j < 4; j++)
        if (valid[j]) {
            int p = t + j * 256;
#pragma unroll
            for (int u = 0; u < 8; u++) c1s[u][p] = acc[j][u];
        }
    __syncthreads();
    if (t < 196) {
        const int ph = t / 14, pw = t % 14;
        ushort hv[8], lv[8];
#pragma unroll
        for (int u = 0; u < 8; u++) {
            float m = c1s[u][(2 * ph) * 30 + 2 * pw];
#pragma unroll
            for (int q = 1; q < 9; q++) {
                int dy = q / 3, dx = q % 3;
                m = fmaxf(m, c1s[u][(2 * ph + dy) * 30 + 2 * pw + dx]);
            }
            float o = fmaxf(m + b1[oc0 + u], 0.f);
            split_bf16(o, hv[u], lv[u]);
        }
        size_t ob = (((size_t)b * 18 + ph + 2) * 18 + pw + 2) * 96 + oc0;
        *(bf16x8*)&h1hi[ob] = *(bf16x8*)&hv[0];
        *(bf16x8*)&h1lo[ob] = *(bf16x8*)&lv[0];
    }
}

// ---------------- split-bf16 MFMA implicit-GEMM conv v4 ---------------------
// r5 body + flat grid with XCD-chunked bijective swizzle (G % 8 == 0).
// LDS XOR-swizzled [row][8 grans], gran g of row r = part g^(r&7).
template <int BM, int IC, int H, int W, int OH, int OW, int OC, int NM>
__global__ __launch_bounds__(256, 2) void convmfma4_k(
        const ushort* __restrict__ ah, const ushort* __restrict__ al,
        const ushort* __restrict__ wh, const ushort* __restrict__ wl,
        const float* __restrict__ bias, float* __restrict__ C) {
    constexpr int K = 25 * IC;
    constexpr int MI = BM / 32;
    constexpr int G = NM * (OC / 128);
    __shared__ ushort At[BM * 64];
    __shared__ ushort Bt[128 * 64];
    const int t = threadIdx.x;
    const int lane = t & 63, wv = t >> 6;
    const int id = blockIdx.x;
    const int id2 = (id & 7) * (G >> 3) + (id >> 3);
    const int n0 = (id2 / NM) * 128;
    const int m0 = (id2 % NM) * BM;
    const int wm = (wv >> 1) * (BM / 2);
    const int wn = (wv & 1) * 64;

    // staging thread geometry
    const int srow = lane >> 3;          // row-in-group 0..7 (== r&7)
    const int slot = lane & 7;           // stored granule
    const int part = slot ^ srow;        // logical part 0..7
    const bool hiA = part < 4;
    const int pk = (part & 3) * 8;       // k-elem offset within 32-slab

    int arb[MI];
#pragma unroll
    for (int rr = 0; rr < MI; rr++) {
        int r = wv * (BM / 4) + rr * 8 + srow;
        int m = m0 + r;
        int b = m / (OH * OW), pxy = m % (OH * OW);
        int oh = pxy / OW, ow = pxy % OW;
        arb[rr] = ((b * H + oh) * W + ow) * IC + pk;
    }
    const ushort* __restrict__ abase = hiA ? ah : al;
    size_t brb[4];
#pragma unroll
    for (int rr = 0; rr < 4; rr++) {
        int r = wv * 32 + rr * 8 + srow;
        brb[rr] = (size_t)(n0 + r) * K + pk;
    }
    const ushort* __restrict__ bbase = hiA ? wh : wl;

    f32x4 acc[MI][4];
#pragma unroll
    for (int i = 0; i < MI; i++)
#pragma unroll
        for (int j = 0; j < 4; j++) acc[i][j] = (f32x4)(0.f);

    const int q = lane >> 4;     // frag k-gran 0..3
    const int fr = lane & 15;

    for (int k0 = 0; k0 < K; k0 += 32) {
        const int tap = k0 / IC;
        const int koff = ((tap / 5) * W + (tap % 5)) * IC + (k0 - tap * IC);

        bf16x8 sa[MI], sb[4];
#pragma unroll
        for (int rr = 0; rr < MI; rr++)
            sa[rr] = *(const bf16x8*)&abase[arb[rr] + koff];
#pragma unroll
        for (int rr = 0; rr < 4; rr++)
            sb[rr] = *(const bf16x8*)&bbase[brb[rr] + k0];
        __syncthreads();
#pragma unroll
        for (int rr = 0; rr < MI; rr++) {
            int r = wv * (BM / 4) + rr * 8 + srow;
            *(bf16x8*)&At[r * 64 + slot * 8] = sa[rr];
        }
#pragma unroll
        for (int rr = 0; rr < 4; rr++) {
            int r = wv * 32 + rr * 8 + srow;
            *(bf16x8*)&Bt[r * 64 + slot * 8] = sb[rr];
        }
        __syncthreads();

        bf16x8 afh[MI], afl[MI], bfh[4], bfl[4];
#pragma unroll
        for (int i = 0; i < MI; i++) {
            int row = wm + fr + i * 16;
            afh[i] = *(const bf16x8*)&At[row * 64 + ((q ^ (row & 7)) << 3)];
            afl[i] = *(const bf16x8*)&At[row * 64 + (((4 | q) ^ (row & 7)) << 3)];
        }
#pragma unroll
        for (int j = 0; j < 4; j++) {
            int row = wn + fr + j * 16;
            bfh[j] = *(const bf16x8*)&Bt[row * 64 + ((q ^ (row & 7)) << 3)];
            bfl[j] = *(const bf16x8*)&Bt[row * 64 + (((4 | q) ^ (row & 7)) << 3)];
        }
#pragma unroll
        for (int i = 0; i < MI; i++)
#pragma unroll
            for (int j = 0; j < 4; j++) {
                acc[i][j] = __builtin_amdgcn_mfma_f32_16x16x32_bf16(
                    afh[i], bfh[j], acc[i][j], 0, 0, 0);
                acc[i][j] = __builtin_amdgcn_mfma_f32_16x16x32_bf16(
                    afh[i], bfl[j], acc[i][j], 0, 0, 0);
                acc[i][j] = __builtin_amdgcn_mfma_f32_16x16x32_bf16(
                    afl[i], bfh[j], acc[i][j], 0, 0, 0);
            }
    }

    const int crow0 = (lane >> 4) * 4;
    const int ccol = lane & 15;
#pragma unroll
    for (int i = 0; i < MI; i++) {
        int gm = m0 + wm + i * 16 + crow0;
#pragma unroll
        for (int j = 0; j < 4; j++) {
            int gn = n0 + wn + j * 16 + ccol;
            float bb = bias[gn];
#pragma unroll
            for (int r = 0; r < 4; r++)
                C[(size_t)(gm + r) * OC + gn] = acc[i][j][r] + bb;
        }
    }
}

// ---------------- pool2: f32 conv2 out -> pre-split hi/lo padded NHWC -------
__global__ void pool2_k(const float* __restrict__ in, ushort* __restrict__ ohi,
                        ushort* __restrict__ olo) {
    int idx = blockIdx.x * 256 + threadIdx.x;
    if (idx >= 512 * 36 * 128) return;
    int c = idx & 127;
    int tmp = idx >> 7;
    int pw = tmp % 6;
    int tmp2 = tmp / 6;
    int ph = tmp2 % 6;
    int b = tmp2 / 6;
    size_t base = (((size_t)b * 14 + 2 * ph) * 14 + 2 * pw) * 128 + c;
    float m = -3.4e38f;
#pragma unroll
    for (int dy = 0; dy < 3; dy++)
#pragma unroll
        for (int dx = 0; dx < 3; dx++)
            m = fmaxf(m, in[base + (dy * 14 + dx) * 128]);
    float v = fmaxf(m, 0.f);
    ushort h, l;
    split_bf16(v, h, l);
    size_t o = (((size_t)b * 10 + ph + 2) * 10 + pw + 2) * 128 + c;
    ohi[o] = h;
    olo[o] = l;
}

// ---------------- pool3: NHWC [512][6][6][256] -> h3 [512][1024] NCHW -------
__global__ void pool3_k(const float* __restrict__ in, float* __restrict__ h3) {
    int idx = blockIdx.x * 256 + threadIdx.x;
    if (idx >= 512 * 4 * 256) return;
    int c = idx & 255;
    int pw = (idx >> 8) & 1;
    int ph = (idx >> 9) & 1;
    int b = idx >> 10;
    size_t base = (((size_t)b * 6 + 2 * ph) * 6 + 2 * pw) * 256 + c;
    float m = -3.4e38f;
#pragma unroll
    for (int dy = 0; dy < 3; dy++)
#pragma unroll
        for (int dx = 0; dx < 3; dx++)
            m = fmaxf(m, in[base + (dy * 6 + dx) * 256]);
    h3[(size_t)b * 1024 + c * 4 + ph * 2 + pw] = fmaxf(m, 0.f);
}

// ---------------- 64x64 tiled f32 GEMM (FC layers) --------------------------
template <int TRANSB, int RELUW, int BIAS, int RELUOUT, int DUAL>
__global__ __launch_bounds__(256) void gemm_k(
        const float* __restrict__ A, const float* __restrict__ Bm,
        const float* __restrict__ bias, float* __restrict__ C,
        float* __restrict__ C2, int K, int N) {
    __shared__ float As[16][68];
    __shared__ float Bs[16][68];
    __shared__ float Bs2[DUAL ? 16 : 1][68];
    const int t = threadIdx.x;
    const int n0 = blockIdx.x * 64;
    const int m0 = blockIdx.y * 64;
    const int tm = t & 15, tn = t >> 4;

    float acc[16];
    float acc2[DUAL ? 16 : 1];
#pragma unroll
    for (int i = 0; i < 16; i++) acc[i] = 0.f;
    if constexpr (DUAL) {
#pragma unroll
        for (int i = 0; i < 16; i++) acc2[i] = 0.f;
    }

    const int ar = t >> 2, ak = (t & 3) << 2;
    const int bk = t >> 4, bn = (t & 15) << 2;

    for (int k0 = 0; k0 < K; k0 += 16) {
        float4 av = *(const float4*)&A[(size_t)(m0 + ar) * K + k0 + ak];
        float4 bv;
        if constexpr (TRANSB) {
            bv = *(const float4*)&Bm[(size_t)(n0 + ar) * K + k0 + ak];
        } else {
            bv = *(const float4*)&Bm[(size_t)(k0 + bk) * N + n0 + bn];
        }
        if constexpr (RELUW) {
            bv.x = fmaxf(bv.x, 0.f); bv.y = fmaxf(bv.y, 0.f);
            bv.z = fmaxf(bv.z, 0.f); bv.w = fmaxf(bv.w, 0.f);
        }
        __syncthreads();
        As[ak + 0][ar] = av.x; As[ak + 1][ar] = av.y;
        As[ak + 2][ar] = av.z; As[ak + 3][ar] = av.w;
        if constexpr (TRANSB) {
            Bs[ak + 0][ar] = bv.x; Bs[ak + 1][ar] = bv.y;
            Bs[ak + 2][ar] = bv.z; Bs[ak + 3][ar] = bv.w;
            if constexpr (DUAL) {
                Bs2[ak + 0][ar] = fmaxf(bv.x, 0.f);
                Bs2[ak + 1][ar] = fmaxf(bv.y, 0.f);
                Bs2[ak + 2][ar] = fmaxf(bv.z, 0.f);
                Bs2[ak + 3][ar] = fmaxf(bv.w, 0.f);
            }
        } else {
            *(float4*)&Bs[bk][bn] = bv;
        }
        __syncthreads();
#pragma unroll
        for (int kk = 0; kk < 16; kk++) {
            float4 a4 = *(const float4*)&As[kk][tm * 4];
            float4 b4 = *(const float4*)&Bs[kk][tn * 4];
            const float* ap = &a4.x;
            const float* bp = &b4.x;
            if constexpr (DUAL) {
                float4 b4p = *(const float4*)&Bs2[kk][tn * 4];
                const float* bpp = &b4p.x;
#pragma unroll
                for (int i = 0; i < 4; i++)
#pragma unroll
                    for (int j = 0; j < 4; j++) {
                        acc[i * 4 + j] = fmaf(ap[i], bp[j], acc[i * 4 + j]);
                        acc2[i * 4 + j] = fmaf(ap[i], bpp[j], acc2[i * 4 + j]);
                    }
            } else {
#pragma unroll
                for (int i = 0; i < 4; i++)
#pragma unroll
                    for (int j = 0; j < 4; j++)
                        acc[i * 4 + j] = fmaf(ap[i], bp[j], acc[i * 4 + j]);
            }
        }
    }

#pragma unroll
    for (int i = 0; i < 4; i++) {
        size_t row = (size_t)(m0 + tm * 4 + i) * N + n0 + tn * 4;
        float4 o;
#pragma unroll
        for (int j = 0; j < 4; j++) {
            float v = acc[i * 4 + j];
            if constexpr (BIAS) v += bias[n0 + tn * 4 + j];
            if constexpr (RELUOUT) v = fmaxf(v, 0.f);
            (&o.x)[j] = v;
        }
        *(float4*)&C[row] = o;
        if constexpr (DUAL) {
            float4 o2;
#pragma unroll
            for (int j = 0; j < 4; j++) (&o2.x)[j] = acc2[i * 4 + j];
            *(float4*)&C2[row] = o2;
        }
    }
}

// ---------------- h6 GEMM: split-bf16 MFMA, BM=64 BN=64 ---------------------
__global__ __launch_bounds__(256, 2) void gemmh6_k(
        const float* __restrict__ A, const ushort* __restrict__ wh,
        const ushort* __restrict__ wl, const float* __restrict__ bias,
        float* __restrict__ C) {
    __shared__ ushort Ah[64][40];
    __shared__ ushort Al[64][40];
    __shared__ ushort Bh[64][40];
    __shared__ ushort Bl[64][40];
    const int t = threadIdx.x;
    const int n0 = blockIdx.x * 64;
    const int m0 = blockIdx.y * 64;
    const int lane = t & 63, wv = t >> 6;
    const int wm = (wv >> 1) * 32, wn = (wv & 1) * 32;
    const int row = t & 63, kq = t >> 6;

    f32x4 acc[2][2];
#pragma unroll
    for (int i = 0; i < 2; i++)
#pragma unroll
        for (int j = 0; j < 2; j++) acc[i][j] = (f32x4)(0.f);

    const int kp = (lane >> 4) * 8;

    for (int k0 = 0; k0 < 2048; k0 += 32) {
        float4 a0 = *(const float4*)&A[(size_t)(m0 + row) * 2048 + k0 + kq * 8];
        float4 a1 = *(const float4*)&A[(size_t)(m0 + row) * 2048 + k0 + kq * 8 + 4];
        bf16x8 bh8 = *(const bf16x8*)&wh[(size_t)(n0 + row) * 2048 + k0 + kq * 8];
        bf16x8 bl8 = *(const bf16x8*)&wl[(size_t)(n0 + row) * 2048 + k0 + kq * 8];
        __syncthreads();
        ushort4 h0, l0, h1, l1;
        split_bf16(a0.x, h0.x, l0.x); split_bf16(a0.y, h0.y, l0.y);
        split_bf16(a0.z, h0.z, l0.z); split_bf16(a0.w, h0.w, l0.w);
        split_bf16(a1.x, h1.x, l1.x); split_bf16(a1.y, h1.y, l1.y);
        split_bf16(a1.z, h1.z, l1.z); split_bf16(a1.w, h1.w, l1.w);
        *(ushort4*)&Ah[row][kq * 8] = h0;
        *(ushort4*)&Ah[row][kq * 8 + 4] = h1;
        *(ushort4*)&Al[row][kq * 8] = l0;
        *(ushort4*)&Al[row][kq * 8 + 4] = l1;
        *(bf16x8*)&Bh[row][kq * 8] = bh8;
        *(bf16x8*)&Bl[row][kq * 8] = bl8;
        __syncthreads();

        bf16x8 afh[2], afl[2], bfh[2], bfl[2];
#pragma unroll
        for (int i = 0; i < 2; i++) {
            afh[i] = *(bf16x8*)&Ah[wm + i * 16 + (lane & 15)][kp];
            afl[i] = *(bf16x8*)&Al[wm + i * 16 + (lane & 15)][kp];
            bfh[i] = *(bf16x8*)&Bh[wn + i * 16 + (lane & 15)][kp];
            bfl[i] = *(bf16x8*)&Bl[wn + i * 16 + (lane & 15)][kp];
        }
#pragma unroll
        for (int i = 0; i < 2; i++)
#pragma unroll
            for (int j = 0; j < 2; j++) {
                acc[i][j] = __builtin_amdgcn_mfma_f32_16x16x32_bf16(
                    afh[i], bfh[j], acc[i][j], 0, 0, 0);
                acc[i][j] = __builtin_amdgcn_mfma_f32_16x16x32_bf16(
                    afh[i], bfl[j], acc[i][j], 0, 0, 0);
                acc[i][j] = __builtin_amdgcn_mfma_f32_16x16x32_bf16(
                    afl[i], bfh[j], acc[i][j], 0, 0, 0);
            }
    }

#pragma unroll
    for (int i = 0; i < 2; i++) {
        int gm = m0 + wm + i * 16 + (lane >> 4) * 4;
#pragma unroll
        for (int j = 0; j < 2; j++) {
            int gn = n0 + wn + j * 16 + (lane & 15);
            float bb = bias[gn];
#pragma unroll
            for (int r = 0; r < 4; r++)
                C[(size_t)(gm + r) * 2048 + gn] = fmaxf(acc[i][j][r] + bb, 0.f);
        }
    }
}

// ---------------- zlab[b] = dot(h6_eb[b], relu(W3[label[b]])) ----------------
__global__ __launch_bounds__(256) void zlab_k(
        const float* __restrict__ h6eb, const float* __restrict__ w3,
        const int* __restrict__ label, float* __restrict__ zlab) {
    __shared__ float red[4];
    const int b = blockIdx.x, t = threadIdx.x;
    const int lab = label[b];
    const float4* hp = (const float4*)(h6eb + (size_t)b * 2048);
    const float4* wp = (const float4*)(w3 + (size_t)lab * 2048);
    float s = 0.f;
    for (int i = t; i < 512; i += 256) {
        float4 h = hp[i], w = wp[i];
        s += h.x * fmaxf(w.x, 0.f) + h.y * fmaxf(w.y, 0.f) +
             h.z * fmaxf(w.z, 0.f) + h.w * fmaxf(w.w, 0.f);
    }
#pragma unroll
    for (int off = 32; off > 0; off >>= 1) s += __shfl_down(s, off, 64);
    if ((t & 63) == 0) red[t >> 6] = s;
    __syncthreads();
    if (t == 0) zlab[b] = red[0] + red[1] + red[2] + red[3];
}

// ---------------- s2 elementwise ----------------
__global__ void s2_k(const float* __restrict__ h6eb, const float* __restrict__ z2,
                     const float* __restrict__ w3, const int* __restrict__ label,
                     const float* __restrict__ zlab, float* __restrict__ s2) {
    int idx = blockIdx.x * 256 + threadIdx.x;
    int b = idx >> 11, j = idx & 2047;
    float zl = zlab[b], zv = z2[idx];
    float v = 0.f;
    if (zl > 0.f && zv > 0.f) {
        float wp = fmaxf(w3[(size_t)label[b] * 2048 + j], 0.f);
        v = h6eb[idx] * wp / (zl * zv);
    }
    s2[idx] = v;
}

// ---------------- excitation dropout ----------------
__global__ void edrop_k(const float* __restrict__ h5, const float* __restrict__ t,
                        const float* __restrict__ noise, float* __restrict__ hed) {
    int idx = blockIdx.x * 256 + threadIdx.x;
    float pe = h5[idx] * t[idx];
    float num = 1023.5f * pe;
    float retain = 1.f - num / (num + 0.5f * (1.f - pe));
    float m = (noise[idx] < retain) ? 1.f : 0.f;
    hed[idx] = (retain > 0.f) ? h5[idx] * m / retain : 0.f;
}

// ---------------- final fc3 ----------------
__global__ void fc3_out_k(const float* __restrict__ h6, const float* __restrict__ w,
                          const float* __restrict__ bias, float* __restrict__ out) {
    int idx = blockIdx.x * 256 + threadIdx.x;
    if (idx >= 5120) return;
    int b = idx / 10, c = idx % 10;
    const float4* hp = (const float4*)(h6 + (size_t)b * 2048);
    const float4* wp = (const float4*)(w + (size_t)c * 2048);
    float s = 0.f;
    for (int i = 0; i < 512; i++) {
        float4 h = hp[i], ww = wp[i];
        s += h.x * ww.x + h.y * ww.y + h.z * ww.z + h.w * ww.w;
    }
    out[idx] = s + bias[c];
}

// ---------------------------------------------------------------------------
extern "C" void kernel_launch(void* const* d_in, const int* in_sizes, int n_in,
                              void* d_out, int out_size, void* d_ws, size_t ws_size,
                              hipStream_t stream) {
    const float* x       = (const float*)d_in[0];
    const float* noise   = (const float*)d_in[1];
    const float* conv1_w = (const float*)d_in[2];
    const float* conv1_b = (const float*)d_in[3];
    const float* conv2_w = (const float*)d_in[4];
    const float* conv2_b = (const float*)d_in[5];
    const float* conv3_w = (const float*)d_in[6];
    const float* conv3_b = (const float*)d_in[7];
    const float* fc1_w   = (const float*)d_in[8];
    const float* fc1_b   = (const float*)d_in[9];
    const float* fc2_w   = (const float*)d_in[10];
    const float* fc2_b   = (const float*)d_in[11];
    const float* fc3_w   = (const float*)d_in[12];
    const float* fc3_b   = (const float*)d_in[13];
    const int*   label   = (const int*)d_in[14];
    float* out = (float*)d_out;

    const size_t N_H1 = (size_t)512 * 18 * 18 * 96;   // 15,925,248 elems
    const size_t N_C2 = (size_t)512 * 14 * 14 * 128;  // 12,845,056
    const size_t N_H2 = (size_t)512 * 10 * 10 * 128;  //  6,553,600
    const size_t N_H3 = (size_t)512 * 1024;

    float* ws = (float*)d_ws;
    ushort* h1hi = (ushort*)ws;
    ushort* h1lo = h1hi + N_H1;
    float* c3 = ws;                       // aliases h1 region after conv2
    float* c2 = ws + N_H1;                // N_C2 floats
    float* h5   = c2;                     // fc buffers alias c2 (dead after pool2)
    float* h6eb = c2 + 1 * 1048576;
    float* z2   = c2 + 2 * 1048576;
    float* s2   = c2 + 3 * 1048576;
    float* tb   = c2 + 4 * 1048576;
    float* hed  = c2 + 5 * 1048576;
    float* h6   = c2 + 6 * 1048576;
    float* zlab = c2 + 7 * 1048576;
    ushort* h2hi = (ushort*)(ws + N_H1 + N_C2);
    ushort* h2lo = h2hi + N_H2;
    float* h3  = ws + N_H1 + N_C2 + N_H2;
    float* w1t = h3 + N_H3;                        // 7,200 floats
    ushort* w2sh = (ushort*)(w1t + 7200);
    ushort* w2sl = w2sh + 307200;
    ushort* w3sh = w2sl + 307200;
    ushort* w3sl = w3sh + 819200;
    ushort* w2fh = w3sl + 819200;
    ushort* w2fl = w2fh + 4194304;

    // weight prep
    transw_k<<<(75 * 96 + 255) / 256, 256, 0, stream>>>(conv1_w, w1t, 96, 75);
    splitw_k<<<(307200 + 255) / 256, 256, 0, stream>>>(conv2_w, w2sh, w2sl, 128, 96);
    splitw_k<<<(819200 + 255) / 256, 256, 0, stream>>>(conv3_w, w3sh, w3sl, 256, 128);
    splitw_fc_k<<<16384, 256, 0, stream>>>(fc2_w, w2fh, w2fl, 4194304);

    // zero padded hi/lo buffers
    zero_k<<<2048, 256, 0, stream>>>((float4*)h1hi, (int)(N_H1 / 4));
    zero_k<<<2048, 256, 0, stream>>>((float4*)h2hi, (int)(N_H2 / 4));

    // conv stack
    conv1_v3<<<dim3(512, 12), 256, 0, stream>>>(x, w1t, conv1_b, h1hi, h1lo);
    // conv2: M=100352, BM=128, NM=784, OC=128 -> 784 blocks (swizzled)
    convmfma4_k<128, 96, 18, 18, 14, 14, 128, 784><<<784, 256, 0, stream>>>(
        h1hi, h1lo, w2sh, w2sl, conv2_b, c2);
    pool2_k<<<(512 * 36 * 128 + 255) / 256, 256, 0, stream>>>(c2, h2hi, h2lo);
    // conv3: M=18432, BM=64, NM=288, OC=256 -> 576 blocks (swizzled)
    convmfma4_k<64, 128, 10, 10, 6, 6, 256, 288><<<576, 256, 0, stream>>>(
        h2hi, h2lo, w3sh, w3sl, conv3_b, c3);
    pool3_k<<<(512 * 4 * 256 + 255) / 256, 256, 0, stream>>>(c3, h3);

    // fc1
    gemm_k<1, 0, 1, 1, 0><<<dim3(32, 8), 256, 0, stream>>>(
        h3, fc1_w, fc1_b, h5, nullptr, 1024, 2048);

    // dual: h6_eb, z2
    gemm_k<1, 0, 1, 1, 1><<<dim3(32, 8), 256, 0, stream>>>(
        h5, fc2_w, fc2_b, h6eb, z2, 2048, 2048);

    // EB collapse
    zlab_k<<<512, 256, 0, stream>>>(h6eb, fc3_w, label, zlab);
    s2_k<<<4096, 256, 0, stream>>>(h6eb, z2, fc3_w, label, zlab, s2);

    // t = s2 @ relu(W2)
    gemm_k<0, 1, 0, 0, 0><<<dim3(32, 8), 256, 0, stream>>>(
        s2, fc2_w, nullptr, tb, nullptr, 2048, 2048);

    // excitation dropout
    edrop_k<<<4096, 256, 0, stream>>>(h5, tb, noise, hed);

    // h6 = relu(h_ed W2^T + b)  -- post-mask: MFMA safe
    gemmh6_k<<<dim3(32, 8), 256, 0, stream>>>(hed, w2fh, w2fl, fc2_b, h6);

    // out
    fc3_out_k<<<20, 256, 0, stream>>>(h6, fc3_w, fc3_b, out);
}

// Round 8
// 1007.133 us; speedup vs baseline: 1.6149x; 1.0336x over previous
//
#include <hip/hip_runtime.h>
#include <hip/hip_bf16.h>

// ---------------------------------------------------------------------------
// CNN + EB dropout. Convs = split-bf16 MFMA implicit GEMM over PRE-SPLIT
// bf16 hi/lo NHWC-padded activation buffers. XOR-swizzled LDS.
// r8: conv K-loop rebuilt as T3-minimum 2-phase: double-buffered LDS staged
// via __builtin_amdgcn_global_load_lds (no VGPR round-trip), loads issued
// before the MFMA cluster, ONE barrier per K-step (vmcnt(0) drain at the
// barrier lands after MFMA -> latency hidden). Bit-identical data placement
// vs r7 (LDS dest = base + lane*16 matches the old swizzled ds_write map).
// ---------------------------------------------------------------------------

typedef __attribute__((ext_vector_type(8))) short bf16x8;
typedef __attribute__((ext_vector_type(4))) float f32x4;

__device__ __forceinline__ void split_bf16(float x, ushort& h, ushort& l) {
    __hip_bfloat16 bh = __float2bfloat16(x);
    float fh = __bfloat162float(bh);
    __hip_bfloat16 bl = __float2bfloat16(x - fh);
    h = *(ushort*)&bh;
    l = *(ushort*)&bl;
}

__device__ __forceinline__ void gld_lds16(const void* g, void* l) {
    __builtin_amdgcn_global_load_lds(
        (const __attribute__((address_space(1))) unsigned int*)g,
        (__attribute__((address_space(3))) unsigned int*)l, 16, 0, 0);
}

// ---------------- zero fill ----------------
__global__ void zero_k(float4* __restrict__ p, int n4) {
    int idx = blockIdx.x * 256 + threadIdx.x;
    int stride = gridDim.x * 256;
    float4 z = {0.f, 0.f, 0.f, 0.f};
    for (int i = idx; i < n4; i += stride) p[i] = z;
}

// ---------------- conv1 weight transpose: out[k*OC+oc]=in[oc*K+k] -----------
__global__ void transw_k(const float* __restrict__ in, float* __restrict__ out,
                         int OC, int K) {
    int idx = blockIdx.x * 256 + threadIdx.x;
    if (idx >= OC * K) return;
    int oc = idx / K, k = idx % K;
    out[k * OC + oc] = in[idx];
}

// ---------------- conv weight split: OIHW -> bf16 hi/lo [oc][tap*IC+ic] -----
__global__ void splitw_k(const float* __restrict__ in, ushort* __restrict__ hi,
                         ushort* __restrict__ lo, int OC, int IC) {
    int idx = blockIdx.x * 256 + threadIdx.x;
    if (idx >= OC * IC * 25) return;
    int oc = idx / (IC * 25);
    int r = idx % (IC * 25);
    int ic = r / 25, tap = r % 25;
    float v = in[idx];
    ushort h, l;
    split_bf16(v, h, l);
    size_t k = (size_t)oc * IC * 25 + tap * IC + ic;
    hi[k] = h;
    lo[k] = l;
}

// ---------------- fc2 weight split (same layout [out][in]) ----------------
__global__ void splitw_fc_k(const float* __restrict__ in, ushort* __restrict__ hi,
                            ushort* __restrict__ lo, int total) {
    int idx = blockIdx.x * 256 + threadIdx.x;
    if (idx >= total) return;
    ushort h, l;
    split_bf16(in[idx], h, l);
    hi[idx] = h;
    lo[idx] = l;
}

// ---------------- conv1: f32 VALU, fused pool, writes pre-split hi/lo -------
__global__ __launch_bounds__(256) void conv1_v3(
        const float* __restrict__ x, const float* __restrict__ w1t,
        const float* __restrict__ b1, ushort* __restrict__ h1hi,
        ushort* __restrict__ h1lo) {
    __shared__ float simg[3 * 34 * 34];   // zero-padded (pad=1)
    __shared__ float c1s[8][904];         // raw conv outputs, 900 px
    const int b = blockIdx.x, oc0 = blockIdx.y * 8, t = threadIdx.x;

    for (int i = t; i < 3 * 34 * 34; i += 256) simg[i] = 0.f;
    __syncthreads();
    for (int i = t; i < 3072; i += 256) {
        int ic = i >> 10, r = (i >> 5) & 31, c = i & 31;
        simg[ic * 1156 + (r + 1) * 34 + (c + 1)] = x[(size_t)b * 3072 + i];
    }
    __syncthreads();

    int base[4];
    bool valid[4];
#pragma unroll
    for (int j = 0; j < 4; j++) {
        int p = t + j * 256;
        valid[j] = p < 900;
        int oh = p / 30, ow = p % 30;
        base[j] = valid[j] ? oh * 34 + ow : 0;
    }

    float acc[4][8];
#pragma unroll
    for (int j = 0; j < 4; j++)
#pragma unroll
        for (int u = 0; u < 8; u++) acc[j][u] = 0.f;

#pragma unroll 1
    for (int ic = 0; ic < 3; ic++) {
        const int icb = ic * 1156;
#pragma unroll 1
        for (int kh = 0; kh < 5; kh++) {
#pragma unroll
            for (int kw = 0; kw < 5; kw++) {
                const float4* wr =
                    (const float4*)&w1t[(ic * 25 + kh * 5 + kw) * 96 + oc0];
                float4 w0 = wr[0], w1v = wr[1];
#pragma unroll
                for (int j = 0; j < 4; j++) {
                    float v = simg[icb + base[j] + kh * 34 + kw];
#pragma unroll
                    for (int u = 0; u < 4; u++) {
                        acc[j][u] = fmaf((&w0.x)[u], v, acc[j][u]);
                        acc[j][u + 4] = fmaf((&w1v.x)[u], v, acc[j][u + 4]);
                    }
                }
            }
        }
    }
#pragma unroll
    for (int j = 0; j < 4; j++)
        if (valid[j]) {
            int p = t + j * 256;
#pragma unroll
            for (int u = 0; u < 8; u++) c1s[u][p] = acc[j][u];
        }
    __syncthreads();
    if (t < 196) {
        const int ph = t / 14, pw = t % 14;
        ushort hv[8], lv[8];
#pragma unroll
        for (int u = 0; u < 8; u++) {
            float m = c1s[u][(2 * ph) * 30 + 2 * pw];
#pragma unroll
            for (int q = 1; q < 9; q++) {
                int dy = q / 3, dx = q % 3;
                m = fmaxf(m, c1s[u][(2 * ph + dy) * 30 + 2 * pw + dx]);
            }
            float o = fmaxf(m + b1[oc0 + u], 0.f);
            split_bf16(o, hv[u], lv[u]);
        }
        size_t ob = (((size_t)b * 18 + ph + 2) * 18 + pw + 2) * 96 + oc0;
        *(bf16x8*)&h1hi[ob] = *(bf16x8*)&hv[0];
        *(bf16x8*)&h1lo[ob] = *(bf16x8*)&lv[0];
    }
}

// ---------------- split-bf16 MFMA implicit-GEMM conv v5 ---------------------
// 2-phase double-buffered global_load_lds pipeline. hi/lo arrays must be
// contiguous: lo = hi + aoff (ushort units). XCD-chunked block swizzle.
template <int BM, int IC, int H, int W, int OH, int OW, int OC, int NM>
__global__ __launch_bounds__(256, 2) void convmfma5_k(
        const ushort* __restrict__ ah, int aoff,
        const ushort* __restrict__ wh, int boff,
        const float* __restrict__ bias, float* __restrict__ C) {
    constexpr int K = 25 * IC;
    constexpr int MI = BM / 32;
    constexpr int G = NM * (OC / 128);
    __shared__ ushort At[2][BM * 64];
    __shared__ ushort Bt[2][128 * 64];
    const int t = threadIdx.x;
    const int lane = t & 63, wv = t >> 6;
    const int id = blockIdx.x;
    const int id2 = (id & 7) * (G >> 3) + (id >> 3);
    const int n0 = (id2 / NM) * 128;
    const int m0 = (id2 % NM) * BM;
    const int wm = (wv >> 1) * (BM / 2);
    const int wn = (wv & 1) * 64;

    // staging lane geometry (same mapping as r7's ds_write version:
    // LDS dest for (wv, rr) group == base + lane*16B, so gld_lds matches)
    const int srow = lane >> 3;          // row-in-group 0..7 (== r&7)
    const int slot = lane & 7;           // stored granule
    const int part = slot ^ srow;        // logical part 0..7
    const bool hiA = part < 4;
    const int pk = (part & 3) * 8;       // k-elem offset within 32-slab

    int arb[MI];
#pragma unroll
    for (int rr = 0; rr < MI; rr++) {
        int r = wv * (BM / 4) + rr * 8 + srow;
        int m = m0 + r;
        int b = m / (OH * OW), pxy = m % (OH * OW);
        int oh = pxy / OW, ow = pxy % OW;
        arb[rr] = ((b * H + oh) * W + ow) * IC + pk;
    }
    const ushort* __restrict__ aptr = ah + (hiA ? 0 : aoff);
    size_t brb[4];
#pragma unroll
    for (int rr = 0; rr < 4; rr++) {
        int r = wv * 32 + rr * 8 + srow;
        brb[rr] = (size_t)(n0 + r) * K + pk;
    }
    const ushort* __restrict__ bptr = wh + (hiA ? 0 : boff);

    f32x4 acc[MI][4];
#pragma unroll
    for (int i = 0; i < MI; i++)
#pragma unroll
        for (int j = 0; j < 4; j++) acc[i][j] = (f32x4)(0.f);

    const int q = lane >> 4;     // frag k-gran 0..3
    const int fr = lane & 15;

    auto stage = [&](int buf, int k0s) {
        const int tap = k0s / IC;
        const int koff = ((tap / 5) * W + (tap % 5)) * IC + (k0s - tap * IC);
#pragma unroll
        for (int rr = 0; rr < MI; rr++)
            gld_lds16(aptr + arb[rr] + koff,
                      &At[buf][(wv * (BM / 4) + rr * 8) * 64]);
#pragma unroll
        for (int rr = 0; rr < 4; rr++)
            gld_lds16(bptr + brb[rr] + k0s,
                      &Bt[buf][(wv * 32 + rr * 8) * 64]);
    };

    stage(0, 0);
    __syncthreads();   // drain prologue loads (vmcnt(0) at barrier)

    int cur = 0;
#pragma unroll 1
    for (int k0 = 0; k0 < K; k0 += 32) {
        // fragments from current buffer
        bf16x8 afh[MI], afl[MI], bfh[4], bfl[4];
#pragma unroll
        for (int i = 0; i < MI; i++) {
            int row = wm + fr + i * 16;
            afh[i] = *(const bf16x8*)&At[cur][row * 64 + ((q ^ (row & 7)) << 3)];
            afl[i] = *(const bf16x8*)&At[cur][row * 64 + (((4 | q) ^ (row & 7)) << 3)];
        }
#pragma unroll
        for (int j = 0; j < 4; j++) {
            int row = wn + fr + j * 16;
            bfh[j] = *(const bf16x8*)&Bt[cur][row * 64 + ((q ^ (row & 7)) << 3)];
            bfl[j] = *(const bf16x8*)&Bt[cur][row * 64 + (((4 | q) ^ (row & 7)) << 3)];
        }
        // issue next slab's loads into the other buffer (overlap with MFMA;
        // the vmcnt(0) the compiler emits at the barrier below drains them)
        const int nxt = k0 + 32;
        if (nxt < K) stage(cur ^ 1, nxt);

#pragma unroll
        for (int i = 0; i < MI; i++)
#pragma unroll
            for (int j = 0; j < 4; j++) {
                acc[i][j] = __builtin_amdgcn_mfma_f32_16x16x32_bf16(
                    afh[i], bfh[j], acc[i][j], 0, 0, 0);
                acc[i][j] = __builtin_amdgcn_mfma_f32_16x16x32_bf16(
                    afh[i], bfl[j], acc[i][j], 0, 0, 0);
                acc[i][j] = __builtin_amdgcn_mfma_f32_16x16x32_bf16(
                    afl[i], bfh[j], acc[i][j], 0, 0, 0);
            }
        __syncthreads();
        cur ^= 1;
    }

    const int crow0 = (lane >> 4) * 4;
    const int ccol = lane & 15;
#pragma unroll
    for (int i = 0; i < MI; i++) {
        int gm = m0 + wm + i * 16 + crow0;
#pragma unroll
        for (int j = 0; j < 4; j++) {
            int gn = n0 + wn + j * 16 + ccol;
            float bb = bias[gn];
#pragma unroll
            for (int r = 0; r < 4; r++)
                C[(size_t)(gm + r) * OC + gn] = acc[i][j][r] + bb;
        }
    }
}

// ---------------- pool2: f32 conv2 out -> pre-split hi/lo padded NHWC -------
__global__ void pool2_k(const float* __restrict__ in, ushort* __restrict__ ohi,
                        ushort* __restrict__ olo) {
    int idx = blockIdx.x * 256 + threadIdx.x;
    if (idx >= 512 * 36 * 128) return;
    int c = idx & 127;
    int tmp = idx >> 7;
    int pw = tmp % 6;
    int tmp2 = tmp / 6;
    int ph = tmp2 % 6;
    int b = tmp2 / 6;
    size_t base = (((size_t)b * 14 + 2 * ph) * 14 + 2 * pw) * 128 + c;
    float m = -3.4e38f;
#pragma unroll
    for (int dy = 0; dy < 3; dy++)
#pragma unroll
        for (int dx = 0; dx < 3; dx++)
            m = fmaxf(m, in[base + (dy * 14 + dx) * 128]);
    float v = fmaxf(m, 0.f);
    ushort h, l;
    split_bf16(v, h, l);
    size_t o = (((size_t)b * 10 + ph + 2) * 10 + pw + 2) * 128 + c;
    ohi[o] = h;
    olo[o] = l;
}

// ---------------- pool3: NHWC [512][6][6][256] -> h3 [512][1024] NCHW -------
__global__ void pool3_k(const float* __restrict__ in, float* __restrict__ h3) {
    int idx = blockIdx.x * 256 + threadIdx.x;
    if (idx >= 512 * 4 * 256) return;
    int c = idx & 255;
    int pw = (idx >> 8) & 1;
    int ph = (idx >> 9) & 1;
    int b = idx >> 10;
    size_t base = (((size_t)b * 6 + 2 * ph) * 6 + 2 * pw) * 256 + c;
    float m = -3.4e38f;
#pragma unroll
    for (int dy = 0; dy < 3; dy++)
#pragma unroll
        for (int dx = 0; dx < 3; dx++)
            m = fmaxf(m, in[base + (dy * 6 + dx) * 256]);
    h3[(size_t)b * 1024 + c * 4 + ph * 2 + pw] = fmaxf(m, 0.f);
}

// ---------------- 64x64 tiled f32 GEMM (FC layers) --------------------------
template <int TRANSB, int RELUW, int BIAS, int RELUOUT, int DUAL>
__global__ __launch_bounds__(256) void gemm_k(
        const float* __restrict__ A, const float* __restrict__ Bm,
        const float* __restrict__ bias, float* __restrict__ C,
        float* __restrict__ C2, int K, int N) {
    __shared__ float As[16][68];
    __shared__ float Bs[16][68];
    __shared__ float Bs2[DUAL ? 16 : 1][68];
    const int t = threadIdx.x;
    const int n0 = blockIdx.x * 64;
    const int m0 = blockIdx.y * 64;
    const int tm = t & 15, tn = t >> 4;

    float acc[16];
    float acc2[DUAL ? 16 : 1];
#pragma unroll
    for (int i = 0; i < 16; i++) acc[i] = 0.f;
    if constexpr (DUAL) {
#pragma unroll
        for (int i = 0; i < 16; i++) acc2[i] = 0.f;
    }

    const int ar = t >> 2, ak = (t & 3) << 2;
    const int bk = t >> 4, bn = (t & 15) << 2;

    for (int k0 = 0; k0 < K; k0 += 16) {
        float4 av = *(const float4*)&A[(size_t)(m0 + ar) * K + k0 + ak];
        float4 bv;
        if constexpr (TRANSB) {
            bv = *(const float4*)&Bm[(size_t)(n0 + ar) * K + k0 + ak];
        } else {
            bv = *(const float4*)&Bm[(size_t)(k0 + bk) * N + n0 + bn];
        }
        if constexpr (RELUW) {
            bv.x = fmaxf(bv.x, 0.f); bv.y = fmaxf(bv.y, 0.f);
            bv.z = fmaxf(bv.z, 0.f); bv.w = fmaxf(bv.w, 0.f);
        }
        __syncthreads();
        As[ak + 0][ar] = av.x; As[ak + 1][ar] = av.y;
        As[ak + 2][ar] = av.z; As[ak + 3][ar] = av.w;
        if constexpr (TRANSB) {
            Bs[ak + 0][ar] = bv.x; Bs[ak + 1][ar] = bv.y;
            Bs[ak + 2][ar] = bv.z; Bs[ak + 3][ar] = bv.w;
            if constexpr (DUAL) {
                Bs2[ak + 0][ar] = fmaxf(bv.x, 0.f);
                Bs2[ak + 1][ar] = fmaxf(bv.y, 0.f);
                Bs2[ak + 2][ar] = fmaxf(bv.z, 0.f);
                Bs2[ak + 3][ar] = fmaxf(bv.w, 0.f);
            }
        } else {
            *(float4*)&Bs[bk][bn] = bv;
        }
        __syncthreads();
#pragma unroll
        for (int kk = 0; kk < 16; kk++) {
            float4 a4 = *(const float4*)&As[kk][tm * 4];
            float4 b4 = *(const float4*)&Bs[kk][tn * 4];
            const float* ap = &a4.x;
            const float* bp = &b4.x;
            if constexpr (DUAL) {
                float4 b4p = *(const float4*)&Bs2[kk][tn * 4];
                const float* bpp = &b4p.x;
#pragma unroll
                for (int i = 0; i < 4; i++)
#pragma unroll
                    for (int j = 0; j < 4; j++) {
                        acc[i * 4 + j] = fmaf(ap[i], bp[j], acc[i * 4 + j]);
                        acc2[i * 4 + j] = fmaf(ap[i], bpp[j], acc2[i * 4 + j]);
                    }
            } else {
#pragma unroll
                for (int i = 0; i < 4; i++)
#pragma unroll
                    for (int j = 0; j < 4; j++)
                        acc[i * 4 + j] = fmaf(ap[i], bp[j], acc[i * 4 + j]);
            }
        }
    }

#pragma unroll
    for (int i = 0; i < 4; i++) {
        size_t row = (size_t)(m0 + tm * 4 + i) * N + n0 + tn * 4;
        float4 o;
#pragma unroll
        for (int j = 0; j < 4; j++) {
            float v = acc[i * 4 + j];
            if constexpr (BIAS) v += bias[n0 + tn * 4 + j];
            if constexpr (RELUOUT) v = fmaxf(v, 0.f);
            (&o.x)[j] = v;
        }
        *(float4*)&C[row] = o;
        if constexpr (DUAL) {
            float4 o2;
#pragma unroll
            for (int j = 0; j < 4; j++) (&o2.x)[j] = acc2[i * 4 + j];
            *(float4*)&C2[row] = o2;
        }
    }
}

// ---------------- h6 GEMM: split-bf16 MFMA, BM=64 BN=64 ---------------------
__global__ __launch_bounds__(256, 2) void gemmh6_k(
        const float* __restrict__ A, const ushort* __restrict__ wh,
        const ushort* __restrict__ wl, const float* __restrict__ bias,
        float* __restrict__ C) {
    __shared__ ushort Ah[64][40];
    __shared__ ushort Al[64][40];
    __shared__ ushort Bh[64][40];
    __shared__ ushort Bl[64][40];
    const int t = threadIdx.x;
    const int n0 = blockIdx.x * 64;
    const int m0 = blockIdx.y * 64;
    const int lane = t & 63, wv = t >> 6;
    const int wm = (wv >> 1) * 32, wn = (wv & 1) * 32;
    const int row = t & 63, kq = t >> 6;

    f32x4 acc[2][2];
#pragma unroll
    for (int i = 0; i < 2; i++)
#pragma unroll
        for (int j = 0; j < 2; j++) acc[i][j] = (f32x4)(0.f);

    const int kp = (lane >> 4) * 8;

    for (int k0 = 0; k0 < 2048; k0 += 32) {
        float4 a0 = *(const float4*)&A[(size_t)(m0 + row) * 2048 + k0 + kq * 8];
        float4 a1 = *(const float4*)&A[(size_t)(m0 + row) * 2048 + k0 + kq * 8 + 4];
        bf16x8 bh8 = *(const bf16x8*)&wh[(size_t)(n0 + row) * 2048 + k0 + kq * 8];
        bf16x8 bl8 = *(const bf16x8*)&wl[(size_t)(n0 + row) * 2048 + k0 + kq * 8];
        __syncthreads();
        ushort4 h0, l0, h1, l1;
        split_bf16(a0.x, h0.x, l0.x); split_bf16(a0.y, h0.y, l0.y);
        split_bf16(a0.z, h0.z, l0.z); split_bf16(a0.w, h0.w, l0.w);
        split_bf16(a1.x, h1.x, l1.x); split_bf16(a1.y, h1.y, l1.y);
        split_bf16(a1.z, h1.z, l1.z); split_bf16(a1.w, h1.w, l1.w);
        *(ushort4*)&Ah[row][kq * 8] = h0;
        *(ushort4*)&Ah[row][kq * 8 + 4] = h1;
        *(ushort4*)&Al[row][kq * 8] = l0;
        *(ushort4*)&Al[row][kq * 8 + 4] = l1;
        *(bf16x8*)&Bh[row][kq * 8] = bh8;
        *(bf16x8*)&Bl[row][kq * 8] = bl8;
        __syncthreads();

        bf16x8 afh[2], afl[2], bfh[2], bfl[2];
#pragma unroll
        for (int i = 0; i < 2; i++) {
            afh[i] = *(bf16x8*)&Ah[wm + i * 16 + (lane & 15)][kp];
            afl[i] = *(bf16x8*)&Al[wm + i * 16 + (lane & 15)][kp];
            bfh[i] = *(bf16x8*)&Bh[wn + i * 16 + (lane & 15)][kp];
            bfl[i] = *(bf16x8*)&Bl[wn + i * 16 + (lane & 15)][kp];
        }
#pragma unroll
        for (int i = 0; i < 2; i++)
#pragma unroll
            for (int j = 0; j < 2; j++) {
                acc[i][j] = __builtin_amdgcn_mfma_f32_16x16x32_bf16(
                    afh[i], bfh[j], acc[i][j], 0, 0, 0);
                acc[i][j] = __builtin_amdgcn_mfma_f32_16x16x32_bf16(
                    afh[i], bfl[j], acc[i][j], 0, 0, 0);
                acc[i][j] = __builtin_amdgcn_mfma_f32_16x16x32_bf16(
                    afl[i], bfh[j], acc[i][j], 0, 0, 0);
            }
    }

#pragma unroll
    for (int i = 0; i < 2; i++) {
        int gm = m0 + wm + i * 16 + (lane >> 4) * 4;
#pragma unroll
        for (int j = 0; j < 2; j++) {
            int gn = n0 + wn + j * 16 + (lane & 15);
            float bb = bias[gn];
#pragma unroll
            for (int r = 0; r < 4; r++)
                C[(size_t)(gm + r) * 2048 + gn] = fmaxf(acc[i][j][r] + bb, 0.f);
        }
    }
}

// ---------------- zlab[b] = dot(h6_eb[b], relu(W3[label[b]])) ----------------
__global__ __launch_bounds__(256) void zlab_k(
        const float* __restrict__ h6eb, const float* __restrict__ w3,
        const int* __restrict__ label, float* __restrict__ zlab) {
    __shared__ float red[4];
    const int b = blockIdx.x, t = threadIdx.x;
    const int lab = label[b];
    const float4* hp = (const float4*)(h6eb + (size_t)b * 2048);
    const float4* wp = (const float4*)(w3 + (size_t)lab * 2048);
    float s = 0.f;
    for (int i = t; i < 512; i += 256) {
        float4 h = hp[i], w = wp[i];
        s += h.x * fmaxf(w.x, 0.f) + h.y * fmaxf(w.y, 0.f) +
             h.z * fmaxf(w.z, 0.f) + h.w * fmaxf(w.w, 0.f);
    }
#pragma unroll
    for (int off = 32; off > 0; off >>= 1) s += __shfl_down(s, off, 64);
    if ((t & 63) == 0) red[t >> 6] = s;
    __syncthreads();
    if (t == 0) zlab[b] = red[0] + red[1] + red[2] + red[3];
}

// ---------------- s2 elementwise ----------------
__global__ void s2_k(const float* __restrict__ h6eb, const float* __restrict__ z2,
                     const float* __restrict__ w3, const int* __restrict__ label,
                     const float* __restrict__ zlab, float* __restrict__ s2) {
    int idx = blockIdx.x * 256 + threadIdx.x;
    int b = idx >> 11, j = idx & 2047;
    float zl = zlab[b], zv = z2[idx];
    float v = 0.f;
    if (zl > 0.f && zv > 0.f) {
        float wp = fmaxf(w3[(size_t)label[b] * 2048 + j], 0.f);
        v = h6eb[idx] * wp / (zl * zv);
    }
    s2[idx] = v;
}

// ---------------- excitation dropout ----------------
__global__ void edrop_k(const float* __restrict__ h5, const float* __restrict__ t,
                        const float* __restrict__ noise, float* __restrict__ hed) {
    int idx = blockIdx.x * 256 + threadIdx.x;
    float pe = h5[idx] * t[idx];
    float num = 1023.5f * pe;
    float retain = 1.f - num / (num + 0.5f * (1.f - pe));
    float m = (noise[idx] < retain) ? 1.f : 0.f;
    hed[idx] = (retain > 0.f) ? h5[idx] * m / retain : 0.f;
}

// ---------------- final fc3 ----------------
__global__ void fc3_out_k(const float* __restrict__ h6, const float* __restrict__ w,
                          const float* __restrict__ bias, float* __restrict__ out) {
    int idx = blockIdx.x * 256 + threadIdx.x;
    if (idx >= 5120) return;
    int b = idx / 10, c = idx % 10;
    const float4* hp = (const float4*)(h6 + (size_t)b * 2048);
    const float4* wp = (const float4*)(w + (size_t)c * 2048);
    float s = 0.f;
    for (int i = 0; i < 512; i++) {
        float4 h = hp[i], ww = wp[i];
        s += h.x * ww.x + h.y * ww.y + h.z * ww.z + h.w * ww.w;
    }
    out[idx] = s + bias[c];
}

// ---------------------------------------------------------------------------
extern "C" void kernel_launch(void* const* d_in, const int* in_sizes, int n_in,
                              void* d_out, int out_size, void* d_ws, size_t ws_size,
                              hipStream_t stream) {
    const float* x       = (const float*)d_in[0];
    const float* noise   = (const float*)d_in[1];
    const float* conv1_w = (const float*)d_in[2];
    const float* conv1_b = (const float*)d_in[3];
    const float* conv2_w = (const float*)d_in[4];
    const float* conv2_b = (const float*)d_in[5];
    const float* conv3_w = (const float*)d_in[6];
    const float* conv3_b = (const float*)d_in[7];
    const float* fc1_w   = (const float*)d_in[8];
    const float* fc1_b   = (const float*)d_in[9];
    const float* fc2_w   = (const float*)d_in[10];
    const float* fc2_b   = (const float*)d_in[11];
    const float* fc3_w   = (const float*)d_in[12];
    const float* fc3_b   = (const float*)d_in[13];
    const int*   label   = (const int*)d_in[14];
    float* out = (float*)d_out;

    const size_t N_H1 = (size_t)512 * 18 * 18 * 96;   // 15,925,248 elems
    const size_t N_C2 = (size_t)512 * 14 * 14 * 128;  // 12,845,056
    const size_t N_H2 = (size_t)512 * 10 * 10 * 128;  //  6,553,600
    const size_t N_H3 = (size_t)512 * 1024;

    float* ws = (float*)d_ws;
    ushort* h1hi = (ushort*)ws;
    ushort* h1lo = h1hi + N_H1;           // contiguous: aoff = N_H1
    float* c3 = ws;                       // aliases h1 region after conv2
    float* c2 = ws + N_H1;                // N_C2 floats
    float* h5   = c2;                     // fc buffers alias c2 (dead after pool2)
    float* h6eb = c2 + 1 * 1048576;
    float* z2   = c2 + 2 * 1048576;
    float* s2   = c2 + 3 * 1048576;
    float* tb   = c2 + 4 * 1048576;
    float* hed  = c2 + 5 * 1048576;
    float* h6   = c2 + 6 * 1048576;
    float* zlab = c2 + 7 * 1048576;
    ushort* h2hi = (ushort*)(ws + N_H1 + N_C2);
    ushort* h2lo = h2hi + N_H2;           // contiguous: aoff = N_H2
    float* h3  = ws + N_H1 + N_C2 + N_H2;
    float* w1t = h3 + N_H3;                        // 7,200 floats
    ushort* w2sh = (ushort*)(w1t + 7200);
    ushort* w2sl = w2sh + 307200;                  // contiguous: boff = 307200
    ushort* w3sh = w2sl + 307200;
    ushort* w3sl = w3sh + 819200;                  // contiguous: boff = 819200
    ushort* w2fh = w3sl + 819200;
    ushort* w2fl = w2fh + 4194304;

    // weight prep
    transw_k<<<(75 * 96 + 255) / 256, 256, 0, stream>>>(conv1_w, w1t, 96, 75);
    splitw_k<<<(307200 + 255) / 256, 256, 0, stream>>>(conv2_w, w2sh, w2sl, 128, 96);
    splitw_k<<<(819200 + 255) / 256, 256, 0, stream>>>(conv3_w, w3sh, w3sl, 256, 128);
    splitw_fc_k<<<16384, 256, 0, stream>>>(fc2_w, w2fh, w2fl, 4194304);

    // zero padded hi/lo buffers
    zero_k<<<2048, 256, 0, stream>>>((float4*)h1hi, (int)(N_H1 / 4));
    zero_k<<<2048, 256, 0, stream>>>((float4*)h2hi, (int)(N_H2 / 4));

    // conv stack
    conv1_v3<<<dim3(512, 12), 256, 0, stream>>>(x, w1t, conv1_b, h1hi, h1lo);
    // conv2: M=100352, BM=128, NM=784, OC=128 -> 784 blocks (swizzled)
    convmfma5_k<128, 96, 18, 18, 14, 14, 128, 784><<<784, 256, 0, stream>>>(
        h1hi, (int)N_H1, w2sh, 307200, conv2_b, c2);
    pool2_k<<<(512 * 36 * 128 + 255) / 256, 256, 0, stream>>>(c2, h2hi, h2lo);
    // conv3: M=18432, BM=64, NM=288, OC=256 -> 576 blocks (swizzled)
    convmfma5_k<64, 128, 10, 10, 6, 6, 256, 288><<<576, 256, 0, stream>>>(
        h2hi, (int)N_H2, w3sh, 819200, conv3_b, c3);
    pool3_k<<<(512 * 4 * 256 + 255) / 256, 256, 0, stream>>>(c3, h3);

    // fc1
    gemm_k<1, 0, 1, 1, 0><<<dim3(32, 8), 256, 0, stream>>>(
        h3, fc1_w, fc1_b, h5, nullptr, 1024, 2048);

    // dual: h6_eb, z2
    gemm_k<1, 0, 1, 1, 1><<<dim3(32, 8), 256, 0, stream>>>(
        h5, fc2_w, fc2_b, h6eb, z2, 2048, 2048);

    // EB collapse
    zlab_k<<<512, 256, 0, stream>>>(h6eb, fc3_w, label, zlab);
    s2_k<<<4096, 256, 0, stream>>>(h6eb, z2, fc3_w, label, zlab, s2);

    // t = s2 @ relu(W2)
    gemm_k<0, 1, 0, 0, 0><<<dim3(32, 8), 256, 0, stream>>>(
        s2, fc2_w, nullptr, tb, nullptr, 2048, 2048);

    // excitation dropout
    edrop_k<<<4096, 256, 0, stream>>>(h5, tb, noise, hed);

    // h6 = relu(h_ed W2^T + b)  -- post-mask: MFMA safe
    gemmh6_k<<<dim3(32, 8), 256, 0, stream>>>(hed, w2fh, w2fl, fc2_b, h6);

    // out
    fc3_out_k<<<20, 256, 0, stream>>>(h6, fc3_w, fc3_b, out);
}